// Round 12
// baseline (46.367 us; speedup 1.0000x reference)
//
#include <hip/hip_runtime.h>
#include <stdint.h>

// DGT forward = binary-tree descent on sign(pred_z[node]) + per-leaf lookup.
// R12: kill the dependent-load latency (the real limit, ~2200cy/level from
// R8's counters) by staging levels 0..7 (nodes 0..254) as packed bf16 in
// 134.6KB of LDS. Levels 8..9 read f32 from global. bf16 sign decided with
// EPS_TIE=0.02 guard band; |z|<EPS -> exact f64 dot on ORIGINAL f32 W
// (proven in R11, absmax=0.0). Occupancy is now LDS-capped (1 block/CU),
// so the register allocator gets a full 128-reg budget -> no spills
// (WRITE_SIZE must stay ~8.3MB).
//
// Shapes: x [65536,256] f32, W_pred [1023,256], b_pred [1023],
//         W_or [16,1024], action_stds [16,1024].
// d_out = [out (65536x16) | std (65536x16)] f32.

#define BATCH     65536
#define IN_DIM    256
#define NLEAF     1024
#define OUT_DIM   16
#define LDS_ROWS  255            // nodes 0..254 = levels 0..7
#define ROW_U32   128            // 256 bf16 per row = 128 u32
#define ROW_PAD   132            // +4 u32 pad: spreads row bases over banks
#define STAGE_U32 (LDS_ROWS * ROW_U32)

#define DPP_QUAD_XOR1   0xB1
#define DPP_QUAD_XOR2   0x4E
#define DPP_HALF_MIRROR 0x141

template <int CTRL>
__device__ __forceinline__ float dpp_xfer(float v) {
    return __int_as_float(__builtin_amdgcn_update_dpp(
        0, __float_as_int(v), CTRL, 0xf, 0xf, true));
}
__device__ __forceinline__ float group8_sum(float v) {
    v += dpp_xfer<DPP_QUAD_XOR1>(v);
    v += dpp_xfer<DPP_QUAD_XOR2>(v);
    v += dpp_xfer<DPP_HALF_MIRROR>(v);
    return v;
}
__device__ __forceinline__ float group8_max(float v) {
    v = fmaxf(v, dpp_xfer<DPP_QUAD_XOR1>(v));
    v = fmaxf(v, dpp_xfer<DPP_QUAD_XOR2>(v));
    v = fmaxf(v, dpp_xfer<DPP_HALF_MIRROR>(v));
    return v;
}

__device__ __forceinline__ float blo(uint32_t u) { return __uint_as_float(u << 16); }
__device__ __forceinline__ float bhi(uint32_t u) { return __uint_as_float(u & 0xffff0000u); }

// ---- prep: W_pred rows 0..254 -> packed bf16 (RNE) in d_ws ----
__global__ __launch_bounds__(256) void dgt_prep(
    const float* __restrict__ W, uint32_t* __restrict__ Wb)
{
    int i = blockIdx.x * 256 + threadIdx.x;
    if (i < STAGE_U32) {
        uint32_t ua = __float_as_uint(W[2 * i]);
        uint32_t ub = __float_as_uint(W[2 * i + 1]);
        uint32_t ra = (ua + 0x7fffu + ((ua >> 16) & 1u)) >> 16;
        uint32_t rb = (ub + 0x7fffu + ((ub >> 16) & 1u)) >> 16;
        Wb[i] = ra | (rb << 16);
    }
}

// Exact-sign fallback on ORIGINAL f32 W (group-uniform entry; z uniform).
// x layout: xka = elems k*64+l*8+{0..3}, xkb = +{4..7}.
__device__ __forceinline__ int tree_sign_f64(
    float4 x0a, float4 x0b, float4 x1a, float4 x1b,
    float4 x2a, float4 x2b, float4 x3a, float4 x3b,
    const float* wrow, float bias, int l)
{
    double A0 = 0.0, A1 = 0.0, A2 = 0.0, A3 = 0.0;
#define ACC64(K, XA, XB)                                                     \
    {                                                                        \
        float4 wa = *reinterpret_cast<const float4*>(wrow + (K)*64 + l * 8); \
        float4 wb = *reinterpret_cast<const float4*>(wrow + (K)*64 + l * 8 + 4); \
        A0 += (double)XA.x * (double)wa.x; A1 += (double)XA.y * (double)wa.y; \
        A2 += (double)XA.z * (double)wa.z; A3 += (double)XA.w * (double)wa.w; \
        A0 += (double)XB.x * (double)wb.x; A1 += (double)XB.y * (double)wb.y; \
        A2 += (double)XB.z * (double)wb.z; A3 += (double)XB.w * (double)wb.w; \
    }
    ACC64(0, x0a, x0b) ACC64(1, x1a, x1b) ACC64(2, x2a, x2b) ACC64(3, x3a, x3b)
#undef ACC64
    double Z = (A0 + A1) + (A2 + A3);
    #pragma unroll
    for (int off = 4; off > 0; off >>= 1)
        Z += __shfl_xor(Z, off, 64);
    Z += (double)bias;
    return (Z < 0.0) ? 1 : 0;
}

// ---- main: 512 threads = 8 waves; 8-lane groups -> 64 samples/block ----
__global__ __launch_bounds__(512, 2) void dgt_main(
    const float* __restrict__ x,
    const uint32_t* __restrict__ Wb,
    const float* __restrict__ W_pred,
    const float* __restrict__ b_pred,
    const float* __restrict__ W_or,
    const float* __restrict__ a_std,
    float* __restrict__ out)
{
    __shared__ __align__(16) uint32_t sW[LDS_ROWS * ROW_PAD];

    // Cooperative stage: ws bf16 rows -> LDS with +4-u32/row padding.
    {
        const uint4* src = reinterpret_cast<const uint4*>(Wb);
        #pragma unroll
        for (int s = 0; s < 16; ++s) {
            int q = threadIdx.x + s * 512;          // uint4 index
            if (q < STAGE_U32 / 4) {
                int j   = q * 4;                    // u32 index
                int row = j >> 7;                   // /128
                int col = j & 127;
                uint4 v = src[q];
                *reinterpret_cast<uint4*>(&sW[row * ROW_PAD + col]) = v;
            }
        }
    }
    __syncthreads();

    const int lane = threadIdx.x & 63;
    const int wid  = threadIdx.x >> 6;   // wave (0..7)
    const int l    = lane & 7;           // lane within 8-group
    const int g    = lane >> 3;          // group (sample) within wave
    const int sample = blockIdx.x * 64 + wid * 8 + g;

    // x: lane l holds elems k*64 + l*8 + {0..7}, k=0..3.
    const float* xrow = x + (size_t)sample * IN_DIM;
    float4 x0a = *reinterpret_cast<const float4*>(xrow +   0 + l * 8);
    float4 x0b = *reinterpret_cast<const float4*>(xrow +   4 + l * 8);
    float4 x1a = *reinterpret_cast<const float4*>(xrow +  64 + l * 8);
    float4 x1b = *reinterpret_cast<const float4*>(xrow +  68 + l * 8);
    float4 x2a = *reinterpret_cast<const float4*>(xrow + 128 + l * 8);
    float4 x2b = *reinterpret_cast<const float4*>(xrow + 132 + l * 8);
    float4 x3a = *reinterpret_cast<const float4*>(xrow + 192 + l * 8);
    float4 x3b = *reinterpret_cast<const float4*>(xrow + 196 + l * 8);

    int node = 0, pos = 0;
    float bcur = b_pred[0];

    // Levels 0..7: bf16 row from LDS (dependent hop ~= ds_read latency).
    #pragma unroll
    for (int lvl = 0; lvl < 8; ++lvl) {
        const uint32_t* wr = sW + node * ROW_PAD;
        uint4 u0 = *reinterpret_cast<const uint4*>(wr +  0 + l * 4);
        uint4 u1 = *reinterpret_cast<const uint4*>(wr + 32 + l * 4);
        uint4 u2 = *reinterpret_cast<const uint4*>(wr + 64 + l * 4);
        uint4 u3 = *reinterpret_cast<const uint4*>(wr + 96 + l * 4);

        float bL = b_pred[2 * node + 1];
        float bR = b_pred[2 * node + 2];

        float a0 = 0.f, a1 = 0.f, a2 = 0.f, a3 = 0.f;
#define ACCB(U, XA, XB)                                     \
        a0 += XA.x * blo(U.x); a1 += XA.y * bhi(U.x);       \
        a2 += XA.z * blo(U.y); a3 += XA.w * bhi(U.y);       \
        a0 += XB.x * blo(U.z); a1 += XB.y * bhi(U.z);       \
        a2 += XB.z * blo(U.w); a3 += XB.w * bhi(U.w);
        ACCB(u0, x0a, x0b)
        ACCB(u1, x1a, x1b)
        ACCB(u2, x2a, x2b)
        ACCB(u3, x3a, x3b)
#undef ACCB
        float z = group8_sum((a0 + a1) + (a2 + a3)) + bcur;

        int right;
        if (__builtin_expect(fabsf(z) >= 0.02f, 1))   // bf16 guard band
            right = (z < 0.f) ? 1 : 0;
        else
            right = tree_sign_f64(x0a, x0b, x1a, x1b, x2a, x2b, x3a, x3b,
                                  W_pred + (size_t)node * IN_DIM, bcur, l);

        pos  = 2 * pos + right;
        node = 2 * node + 1 + right;
        bcur = right ? bR : bL;
    }

    // Levels 8..9: f32 rows from global (same x layout).
    #pragma unroll
    for (int lvl = 8; lvl < 10; ++lvl) {
        const float* wrow = W_pred + (size_t)node * IN_DIM;
        float4 w0a = *reinterpret_cast<const float4*>(wrow +   0 + l * 8);
        float4 w0b = *reinterpret_cast<const float4*>(wrow +   4 + l * 8);
        float4 w1a = *reinterpret_cast<const float4*>(wrow +  64 + l * 8);
        float4 w1b = *reinterpret_cast<const float4*>(wrow +  68 + l * 8);
        float4 w2a = *reinterpret_cast<const float4*>(wrow + 128 + l * 8);
        float4 w2b = *reinterpret_cast<const float4*>(wrow + 132 + l * 8);
        float4 w3a = *reinterpret_cast<const float4*>(wrow + 192 + l * 8);
        float4 w3b = *reinterpret_cast<const float4*>(wrow + 196 + l * 8);

        float bL = 0.f, bR = 0.f;
        if (lvl < 9) {
            bL = b_pred[2 * node + 1];
            bR = b_pred[2 * node + 2];
        }

        float a0, a1, a2, a3;
        a0  = x0a.x * w0a.x; a1  = x0a.y * w0a.y; a2  = x0a.z * w0a.z; a3  = x0a.w * w0a.w;
        a0 += x0b.x * w0b.x; a1 += x0b.y * w0b.y; a2 += x0b.z * w0b.z; a3 += x0b.w * w0b.w;
        a0 += x1a.x * w1a.x; a1 += x1a.y * w1a.y; a2 += x1a.z * w1a.z; a3 += x1a.w * w1a.w;
        a0 += x1b.x * w1b.x; a1 += x1b.y * w1b.y; a2 += x1b.z * w1b.z; a3 += x1b.w * w1b.w;
        a0 += x2a.x * w2a.x; a1 += x2a.y * w2a.y; a2 += x2a.z * w2a.z; a3 += x2a.w * w2a.w;
        a0 += x2b.x * w2b.x; a1 += x2b.y * w2b.y; a2 += x2b.z * w2b.z; a3 += x2b.w * w2b.w;
        a0 += x3a.x * w3a.x; a1 += x3a.y * w3a.y; a2 += x3a.z * w3a.z; a3 += x3a.w * w3a.w;
        a0 += x3b.x * w3b.x; a1 += x3b.y * w3b.y; a2 += x3b.z * w3b.z; a3 += x3b.w * w3b.w;
        float z = group8_sum((a0 + a1) + (a2 + a3)) + bcur;

        int right;
        if (__builtin_expect(fabsf(z) >= 1e-3f, 1))   // f32 guard band
            right = (z < 0.f) ? 1 : 0;
        else
            right = tree_sign_f64(x0a, x0b, x1a, x1b, x2a, x2b, x3a, x3b,
                                  wrow, bcur, l);

        pos  = 2 * pos + right;
        node = 2 * node + 1 + right;
        if (lvl < 9) bcur = right ? bR : bL;
    }
    const int leaf = pos;  // in [0, 1024)

    // Epilogue: lane l covers classes {2l, 2l+1}; tables are cache-resident.
    float zx = W_or[(size_t)(2 * l)     * NLEAF + leaf];
    float zy = W_or[(size_t)(2 * l + 1) * NLEAF + leaf];
    float m  = group8_max(fmaxf(zx, zy));
    float ex = __expf(zx - m), ey = __expf(zy - m);
    float s  = group8_sum(ex + ey);
    *reinterpret_cast<float2*>(out + (size_t)sample * OUT_DIM + 2 * l) =
        make_float2(ex / s, ey / s);

    float dx = a_std[(size_t)(2 * l)     * NLEAF + leaf];
    float dy = a_std[(size_t)(2 * l + 1) * NLEAF + leaf];
    *reinterpret_cast<float2*>(out + (size_t)BATCH * OUT_DIM
                               + (size_t)sample * OUT_DIM + 2 * l) =
        make_float2(fminf(fmaxf(dx, -20.f), 2.f),
                    fminf(fmaxf(dy, -20.f), 2.f));
}

// ---- fallback (ws too small): R8 kernel (best prior clean variant) ----
__device__ __forceinline__ int tree_sign_f64_r8(
    float4 x0, float4 x1, float4 x2, float4 x3,
    float4 x4, float4 x5, float4 x6, float4 x7,
    const float* wrow, float bias, int l)
{
    double A0 = 0.0, A1 = 0.0, A2 = 0.0, A3 = 0.0;
#define ACC64(K, XV)                                                        \
    {                                                                       \
        float4 w = *reinterpret_cast<const float4*>(wrow + (K)*32 + l * 4); \
        A0 += (double)XV.x * (double)w.x; A1 += (double)XV.y * (double)w.y; \
        A2 += (double)XV.z * (double)w.z; A3 += (double)XV.w * (double)w.w; \
    }
    ACC64(0, x0) ACC64(1, x1) ACC64(2, x2) ACC64(3, x3)
    ACC64(4, x4) ACC64(5, x5) ACC64(6, x6) ACC64(7, x7)
#undef ACC64
    double Z = (A0 + A1) + (A2 + A3);
    #pragma unroll
    for (int off = 4; off > 0; off >>= 1)
        Z += __shfl_xor(Z, off, 64);
    Z += (double)bias;
    return (Z < 0.0) ? 1 : 0;
}

__global__ __launch_bounds__(256, 2) void dgt_f32(
    const float* __restrict__ x,
    const float* __restrict__ W_pred,
    const float* __restrict__ b_pred,
    const float* __restrict__ W_or,
    const float* __restrict__ a_std,
    float* __restrict__ out)
{
    const int lane = threadIdx.x & 63;
    const int wid  = threadIdx.x >> 6;
    const int l    = lane & 7;
    const int g    = lane >> 3;
    const int sample = blockIdx.x * 32 + wid * 8 + g;

    const float* xrow = x + (size_t)sample * IN_DIM;
    float4 x0 = *reinterpret_cast<const float4*>(xrow +   0 + l * 4);
    float4 x1 = *reinterpret_cast<const float4*>(xrow +  32 + l * 4);
    float4 x2 = *reinterpret_cast<const float4*>(xrow +  64 + l * 4);
    float4 x3 = *reinterpret_cast<const float4*>(xrow +  96 + l * 4);
    float4 x4 = *reinterpret_cast<const float4*>(xrow + 128 + l * 4);
    float4 x5 = *reinterpret_cast<const float4*>(xrow + 160 + l * 4);
    float4 x6 = *reinterpret_cast<const float4*>(xrow + 192 + l * 4);
    float4 x7 = *reinterpret_cast<const float4*>(xrow + 224 + l * 4);

    int node = 0, pos = 0;
    float bcur = b_pred[0];
    const float* wrow = W_pred;

    #pragma unroll
    for (int lvl = 0; lvl < 10; ++lvl) {
        float4 w0 = *reinterpret_cast<const float4*>(wrow +   0 + l * 4);
        float4 w1 = *reinterpret_cast<const float4*>(wrow +  32 + l * 4);
        float4 w2 = *reinterpret_cast<const float4*>(wrow +  64 + l * 4);
        float4 w3 = *reinterpret_cast<const float4*>(wrow +  96 + l * 4);
        float4 w4 = *reinterpret_cast<const float4*>(wrow + 128 + l * 4);
        float4 w5 = *reinterpret_cast<const float4*>(wrow + 160 + l * 4);
        float4 w6 = *reinterpret_cast<const float4*>(wrow + 192 + l * 4);
        float4 w7 = *reinterpret_cast<const float4*>(wrow + 224 + l * 4);

        float bL = 0.f, bR = 0.f;
        if (lvl < 9) {
            bL = b_pred[2 * node + 1];
            bR = b_pred[2 * node + 2];
        }

        float a0, a1, a2, a3;
        a0  = x0.x * w0.x; a1  = x0.y * w0.y; a2  = x0.z * w0.z; a3  = x0.w * w0.w;
        a0 += x1.x * w1.x; a1 += x1.y * w1.y; a2 += x1.z * w1.z; a3 += x1.w * w1.w;
        a0 += x2.x * w2.x; a1 += x2.y * w2.y; a2 += x2.z * w2.z; a3 += x2.w * w2.w;
        a0 += x3.x * w3.x; a1 += x3.y * w3.y; a2 += x3.z * w3.z; a3 += x3.w * w3.w;
        a0 += x4.x * w4.x; a1 += x4.y * w4.y; a2 += x4.z * w4.z; a3 += x4.w * w4.w;
        a0 += x5.x * w5.x; a1 += x5.y * w5.y; a2 += x5.z * w5.z; a3 += x5.w * w5.w;
        a0 += x6.x * w6.x; a1 += x6.y * w6.y; a2 += x6.z * w6.z; a3 += x6.w * w6.w;
        a0 += x7.x * w7.x; a1 += x7.y * w7.y; a2 += x7.z * w7.z; a3 += x7.w * w7.w;
        float z = group8_sum((a0 + a1) + (a2 + a3)) + bcur;

        int right;
        if (__builtin_expect(fabsf(z) >= 1e-3f, 1))
            right = (z < 0.f) ? 1 : 0;
        else
            right = tree_sign_f64_r8(x0, x1, x2, x3, x4, x5, x6, x7,
                                     wrow, bcur, l);

        pos  = 2 * pos + right;
        node = 2 * node + 1 + right;
        if (lvl < 9) {
            bcur = right ? bR : bL;
            wrow = W_pred + (size_t)node * IN_DIM;
        }
    }
    const int leaf = pos;

    float zx = W_or[(size_t)(2 * l)     * NLEAF + leaf];
    float zy = W_or[(size_t)(2 * l + 1) * NLEAF + leaf];
    float m  = group8_max(fmaxf(zx, zy));
    float ex = __expf(zx - m), ey = __expf(zy - m);
    float s  = group8_sum(ex + ey);
    *reinterpret_cast<float2*>(out + (size_t)sample * OUT_DIM + 2 * l) =
        make_float2(ex / s, ey / s);

    float dx = a_std[(size_t)(2 * l)     * NLEAF + leaf];
    float dy = a_std[(size_t)(2 * l + 1) * NLEAF + leaf];
    *reinterpret_cast<float2*>(out + (size_t)BATCH * OUT_DIM
                               + (size_t)sample * OUT_DIM + 2 * l) =
        make_float2(fminf(fmaxf(dx, -20.f), 2.f),
                    fminf(fmaxf(dy, -20.f), 2.f));
}

extern "C" void kernel_launch(void* const* d_in, const int* in_sizes, int n_in,
                              void* d_out, int out_size, void* d_ws, size_t ws_size,
                              hipStream_t stream) {
    const float* x      = (const float*)d_in[0];
    const float* W_pred = (const float*)d_in[1];
    const float* b_pred = (const float*)d_in[2];
    const float* W_or   = (const float*)d_in[3];
    const float* a_std  = (const float*)d_in[4];
    float* out = (float*)d_out;

    if (ws_size >= (size_t)STAGE_U32 * 4) {
        uint32_t* Wb = (uint32_t*)d_ws;
        hipLaunchKernelGGL(dgt_prep, dim3((STAGE_U32 + 255) / 256), dim3(256),
                           0, stream, W_pred, Wb);
        hipLaunchKernelGGL(dgt_main, dim3(BATCH / 64), dim3(512), 0, stream,
                           x, Wb, W_pred, b_pred, W_or, a_std, out);
    } else {
        hipLaunchKernelGGL(dgt_f32, dim3(BATCH / 32), dim3(256), 0, stream,
                           x, W_pred, b_pred, W_or, a_std, out);
    }
}

// Round 13
// 45.857 us; speedup vs baseline: 1.0111x; 1.0111x over previous
//
#include <hip/hip_runtime.h>
#include <stdint.h>

// DGT forward = binary-tree descent on sign(pred_z[node]) + per-leaf lookup.
// R13: maximize descent-chains per SIMD (the surviving perf law:
// dur ~ 600/chains us; chains = waves/EU x 8, waves/EU = floor(192/VGPR)).
// Register diet to hit VGPR<=48 -> 4 waves/EU -> 32 chains/SIMD:
//  - x held as PACKED BF16 in 16 u32 regs (converted in-register once);
//  - W bf16 (from a 512KB ws copy) consumed in two 8-reg chunks with
//    sched_barrier(0) so the scheduler can't hoist chunk-B loads (R10's
//    spill mechanism was exactly this hoist);
//  - single b_pred[node] load per level, no children prefetch.
// Numerics: both-bf16 dot error sigma ~1.6e-3; EPS_TIE=0.02 ~ 12 sigma.
// |z| < EPS -> exact f64 dot on ORIGINAL f32 x and W (proven: absmax=0.0
// in R11/R12 with the same guard+fallback scheme).
//
// Spill signature to watch: WRITE_SIZE must stay ~8.2MB (output only).

#define BATCH   65536
#define IN_DIM  256
#define NLEVEL  10
#define NLEAF   1024
#define OUT_DIM 16
#define EPS_TIE 0.02f
#define WB_U32  (1023 * 128)   // packed bf16 W: 128 u32 per row

#define DPP_QUAD_XOR1   0xB1
#define DPP_QUAD_XOR2   0x4E
#define DPP_HALF_MIRROR 0x141

template <int CTRL>
__device__ __forceinline__ float dpp_xfer(float v) {
    return __int_as_float(__builtin_amdgcn_update_dpp(
        0, __float_as_int(v), CTRL, 0xf, 0xf, true));
}
__device__ __forceinline__ float group8_sum(float v) {
    v += dpp_xfer<DPP_QUAD_XOR1>(v);
    v += dpp_xfer<DPP_QUAD_XOR2>(v);
    v += dpp_xfer<DPP_HALF_MIRROR>(v);
    return v;
}
__device__ __forceinline__ float group8_max(float v) {
    v = fmaxf(v, dpp_xfer<DPP_QUAD_XOR1>(v));
    v = fmaxf(v, dpp_xfer<DPP_QUAD_XOR2>(v));
    v = fmaxf(v, dpp_xfer<DPP_HALF_MIRROR>(v));
    return v;
}

__device__ __forceinline__ float blo(uint32_t u) { return __uint_as_float(u << 16); }
__device__ __forceinline__ float bhi(uint32_t u) { return __uint_as_float(u & 0xffff0000u); }

// f32 pair -> packed bf16 (RNE), same rounding as the prep kernel.
__device__ __forceinline__ uint32_t pkbf(float a, float b) {
    uint32_t ua = __float_as_uint(a), ub = __float_as_uint(b);
    uint32_t ra = (ua + 0x7fffu + ((ua >> 16) & 1u)) >> 16;
    uint32_t rb = (ub + 0x7fffu + ((ub >> 16) & 1u)) >> 16;
    return ra | (rb << 16);
}

// ---- prep: W_pred f32 -> packed bf16 (RNE) in d_ws ----
__global__ __launch_bounds__(256) void dgt_prep(
    const float* __restrict__ W, uint32_t* __restrict__ Wb)
{
    int i = blockIdx.x * 256 + threadIdx.x;
    if (i < WB_U32) Wb[i] = pkbf(W[2 * i], W[2 * i + 1]);
}

// Rare exact-sign fallback: f64 dot on ORIGINAL f32 x and W (group-uniform
// entry: z is bitwise-uniform across the 8-lane group).
__device__ __forceinline__ int tree_sign_f64(
    const float* __restrict__ xrow, const float* __restrict__ wrow,
    float bias, int l)
{
    double A0 = 0.0, A1 = 0.0, A2 = 0.0, A3 = 0.0;
    #pragma unroll
    for (int k = 0; k < 4; ++k) {
        float4 xa = *reinterpret_cast<const float4*>(xrow + k * 64 + l * 8);
        float4 xb = *reinterpret_cast<const float4*>(xrow + k * 64 + l * 8 + 4);
        float4 wa = *reinterpret_cast<const float4*>(wrow + k * 64 + l * 8);
        float4 wb = *reinterpret_cast<const float4*>(wrow + k * 64 + l * 8 + 4);
        A0 += (double)xa.x * (double)wa.x; A1 += (double)xa.y * (double)wa.y;
        A2 += (double)xa.z * (double)wa.z; A3 += (double)xa.w * (double)wa.w;
        A0 += (double)xb.x * (double)wb.x; A1 += (double)xb.y * (double)wb.y;
        A2 += (double)xb.z * (double)wb.z; A3 += (double)xb.w * (double)wb.w;
    }
    double Z = (A0 + A1) + (A2 + A3);
    #pragma unroll
    for (int off = 4; off > 0; off >>= 1)   // xor involution: uniform result
        Z += __shfl_xor(Z, off, 64);
    Z += (double)bias;
    return (Z < 0.0) ? 1 : 0;
}

// ---- main: 256 threads = 4 waves; 8-lane groups -> 32 samples/block ----
__global__ __launch_bounds__(256, 5) void dgt_b16(
    const float* __restrict__ x,
    const uint32_t* __restrict__ Wb,
    const float* __restrict__ W_pred,
    const float* __restrict__ b_pred,
    const float* __restrict__ W_or,
    const float* __restrict__ a_std,
    float* __restrict__ out)
{
    const int lane = threadIdx.x & 63;
    const int wid  = threadIdx.x >> 6;
    const int l    = lane & 7;           // lane within 8-group
    const int g    = lane >> 3;          // group (sample) within wave
    const int sample = blockIdx.x * 32 + wid * 8 + g;

    // x: lane l owns elems {2c*? ...}: for chunk base c in {0,64,128,192},
    // elems c + 8l + {0..7}. Load f32 in two batches, pack to bf16 in regs.
    const float* xrow = x + (size_t)sample * IN_DIM;
    uint32_t p0, p1, p2, p3, p4, p5, p6, p7, p8, p9, p10, p11, p12, p13, p14, p15;
    {
        float4 a0 = *reinterpret_cast<const float4*>(xrow +   0 + l * 8);
        float4 b0 = *reinterpret_cast<const float4*>(xrow +   4 + l * 8);
        float4 a1 = *reinterpret_cast<const float4*>(xrow +  64 + l * 8);
        float4 b1 = *reinterpret_cast<const float4*>(xrow +  68 + l * 8);
        p0 = pkbf(a0.x, a0.y); p1 = pkbf(a0.z, a0.w);
        p2 = pkbf(b0.x, b0.y); p3 = pkbf(b0.z, b0.w);
        p4 = pkbf(a1.x, a1.y); p5 = pkbf(a1.z, a1.w);
        p6 = pkbf(b1.x, b1.y); p7 = pkbf(b1.z, b1.w);
        float4 a2 = *reinterpret_cast<const float4*>(xrow + 128 + l * 8);
        float4 b2 = *reinterpret_cast<const float4*>(xrow + 132 + l * 8);
        float4 a3 = *reinterpret_cast<const float4*>(xrow + 192 + l * 8);
        float4 b3 = *reinterpret_cast<const float4*>(xrow + 196 + l * 8);
        p8  = pkbf(a2.x, a2.y); p9  = pkbf(a2.z, a2.w);
        p10 = pkbf(b2.x, b2.y); p11 = pkbf(b2.z, b2.w);
        p12 = pkbf(a3.x, a3.y); p13 = pkbf(a3.z, a3.w);
        p14 = pkbf(b3.x, b3.y); p15 = pkbf(b3.z, b3.w);
    }

    int node = 0, pos = 0;

    #pragma unroll
    for (int lvl = 0; lvl < NLEVEL; ++lvl) {
        const uint32_t* wb = Wb + (size_t)node * 128;
        float bcur = b_pred[node];

        // Chunk A: u32 [l*4 .. ] and [32+l*4 ..] -> elems 8l+{0..7}, 64+8l+{0..7}.
        uint4 A0 = *reinterpret_cast<const uint4*>(wb +  0 + l * 4);
        uint4 A1 = *reinterpret_cast<const uint4*>(wb + 32 + l * 4);

        float a0 = 0.f, a1 = 0.f, a2 = 0.f, a3 = 0.f;
#define FMAU(U, P)                                          \
        a0 += blo(U) * blo(P); a1 += bhi(U) * bhi(P);
#define FMA4(UQ, Pa, Pb, Pc, Pd)                            \
        FMAU(UQ.x, Pa) FMAU(UQ.y, Pb) FMAU(UQ.z, Pc) FMAU(UQ.w, Pd)
        FMA4(A0, p0, p1, p2, p3)
        FMA4(A1, p4, p5, p6, p7)

        // Keep chunk-B loads BELOW chunk-A FMAs (W live regs stay 8).
        __builtin_amdgcn_sched_barrier(0);

        uint4 B0 = *reinterpret_cast<const uint4*>(wb + 64 + l * 4);
        uint4 B1 = *reinterpret_cast<const uint4*>(wb + 96 + l * 4);
        FMA4(B0, p8,  p9,  p10, p11)
        FMA4(B1, p12, p13, p14, p15)
#undef FMA4
#undef FMAU

        float z = group8_sum((a0 + a1) + (a2 + a3)) + bcur;

        int right;
        if (__builtin_expect(fabsf(z) >= EPS_TIE, 1))
            right = (z < 0.f) ? 1 : 0;
        else
            right = tree_sign_f64(xrow, W_pred + (size_t)node * IN_DIM,
                                  bcur, l);   // group-uniform entry

        pos  = 2 * pos + right;
        node = 2 * node + 1 + right;
    }
    const int leaf = pos;  // in [0, 1024)

    // Epilogue: lane l covers classes {2l, 2l+1}; tables are cache-resident.
    float zx = W_or[(size_t)(2 * l)     * NLEAF + leaf];
    float zy = W_or[(size_t)(2 * l + 1) * NLEAF + leaf];
    float m  = group8_max(fmaxf(zx, zy));
    float ex = __expf(zx - m), ey = __expf(zy - m);
    float s  = group8_sum(ex + ey);
    *reinterpret_cast<float2*>(out + (size_t)sample * OUT_DIM + 2 * l) =
        make_float2(ex / s, ey / s);

    float dx = a_std[(size_t)(2 * l)     * NLEAF + leaf];
    float dy = a_std[(size_t)(2 * l + 1) * NLEAF + leaf];
    *reinterpret_cast<float2*>(out + (size_t)BATCH * OUT_DIM
                               + (size_t)sample * OUT_DIM + 2 * l) =
        make_float2(fminf(fmaxf(dx, -20.f), 2.f),
                    fminf(fmaxf(dy, -20.f), 2.f));
}

// ---- fallback kernel (ws too small): R8 structure, f32 W direct ----
__device__ __forceinline__ int tree_sign_f64_r8(
    float4 x0, float4 x1, float4 x2, float4 x3,
    float4 x4, float4 x5, float4 x6, float4 x7,
    const float* wrow, float bias, int l)
{
    double A0 = 0.0, A1 = 0.0, A2 = 0.0, A3 = 0.0;
#define ACC64(K, XV)                                                        \
    {                                                                       \
        float4 w = *reinterpret_cast<const float4*>(wrow + (K)*32 + l * 4); \
        A0 += (double)XV.x * (double)w.x; A1 += (double)XV.y * (double)w.y; \
        A2 += (double)XV.z * (double)w.z; A3 += (double)XV.w * (double)w.w; \
    }
    ACC64(0, x0) ACC64(1, x1) ACC64(2, x2) ACC64(3, x3)
    ACC64(4, x4) ACC64(5, x5) ACC64(6, x6) ACC64(7, x7)
#undef ACC64
    double Z = (A0 + A1) + (A2 + A3);
    #pragma unroll
    for (int off = 4; off > 0; off >>= 1)
        Z += __shfl_xor(Z, off, 64);
    Z += (double)bias;
    return (Z < 0.0) ? 1 : 0;
}

__global__ __launch_bounds__(256, 2) void dgt_f32(
    const float* __restrict__ x,
    const float* __restrict__ W_pred,
    const float* __restrict__ b_pred,
    const float* __restrict__ W_or,
    const float* __restrict__ a_std,
    float* __restrict__ out)
{
    const int lane = threadIdx.x & 63;
    const int wid  = threadIdx.x >> 6;
    const int l    = lane & 7;
    const int g    = lane >> 3;
    const int sample = blockIdx.x * 32 + wid * 8 + g;

    const float* xrow = x + (size_t)sample * IN_DIM;
    float4 x0 = *reinterpret_cast<const float4*>(xrow +   0 + l * 4);
    float4 x1 = *reinterpret_cast<const float4*>(xrow +  32 + l * 4);
    float4 x2 = *reinterpret_cast<const float4*>(xrow +  64 + l * 4);
    float4 x3 = *reinterpret_cast<const float4*>(xrow +  96 + l * 4);
    float4 x4 = *reinterpret_cast<const float4*>(xrow + 128 + l * 4);
    float4 x5 = *reinterpret_cast<const float4*>(xrow + 160 + l * 4);
    float4 x6 = *reinterpret_cast<const float4*>(xrow + 192 + l * 4);
    float4 x7 = *reinterpret_cast<const float4*>(xrow + 224 + l * 4);

    int node = 0, pos = 0;
    float bcur = b_pred[0];
    const float* wrow = W_pred;

    #pragma unroll
    for (int lvl = 0; lvl < NLEVEL; ++lvl) {
        float4 w0 = *reinterpret_cast<const float4*>(wrow +   0 + l * 4);
        float4 w1 = *reinterpret_cast<const float4*>(wrow +  32 + l * 4);
        float4 w2 = *reinterpret_cast<const float4*>(wrow +  64 + l * 4);
        float4 w3 = *reinterpret_cast<const float4*>(wrow +  96 + l * 4);
        float4 w4 = *reinterpret_cast<const float4*>(wrow + 128 + l * 4);
        float4 w5 = *reinterpret_cast<const float4*>(wrow + 160 + l * 4);
        float4 w6 = *reinterpret_cast<const float4*>(wrow + 192 + l * 4);
        float4 w7 = *reinterpret_cast<const float4*>(wrow + 224 + l * 4);

        float bL = 0.f, bR = 0.f;
        if (lvl < NLEVEL - 1) {
            bL = b_pred[2 * node + 1];
            bR = b_pred[2 * node + 2];
        }

        float a0, a1, a2, a3;
        a0  = x0.x * w0.x; a1  = x0.y * w0.y; a2  = x0.z * w0.z; a3  = x0.w * w0.w;
        a0 += x1.x * w1.x; a1 += x1.y * w1.y; a2 += x1.z * w1.z; a3 += x1.w * w1.w;
        a0 += x2.x * w2.x; a1 += x2.y * w2.y; a2 += x2.z * w2.z; a3 += x2.w * w2.w;
        a0 += x3.x * w3.x; a1 += x3.y * w3.y; a2 += x3.z * w3.z; a3 += x3.w * w3.w;
        a0 += x4.x * w4.x; a1 += x4.y * w4.y; a2 += x4.z * w4.z; a3 += x4.w * w4.w;
        a0 += x5.x * w5.x; a1 += x5.y * w5.y; a2 += x5.z * w5.z; a3 += x5.w * w5.w;
        a0 += x6.x * w6.x; a1 += x6.y * w6.y; a2 += x6.z * w6.z; a3 += x6.w * w6.w;
        a0 += x7.x * w7.x; a1 += x7.y * w7.y; a2 += x7.z * w7.z; a3 += x7.w * w7.w;
        float z = group8_sum((a0 + a1) + (a2 + a3)) + bcur;

        int right;
        if (__builtin_expect(fabsf(z) >= 1e-3f, 1))
            right = (z < 0.f) ? 1 : 0;
        else
            right = tree_sign_f64_r8(x0, x1, x2, x3, x4, x5, x6, x7,
                                     wrow, bcur, l);

        pos  = 2 * pos + right;
        node = 2 * node + 1 + right;
        if (lvl < NLEVEL - 1) {
            bcur = right ? bR : bL;
            wrow = W_pred + (size_t)node * IN_DIM;
        }
    }
    const int leaf = pos;

    float zx = W_or[(size_t)(2 * l)     * NLEAF + leaf];
    float zy = W_or[(size_t)(2 * l + 1) * NLEAF + leaf];
    float m  = group8_max(fmaxf(zx, zy));
    float ex = __expf(zx - m), ey = __expf(zy - m);
    float s  = group8_sum(ex + ey);
    *reinterpret_cast<float2*>(out + (size_t)sample * OUT_DIM + 2 * l) =
        make_float2(ex / s, ey / s);

    float dx = a_std[(size_t)(2 * l)     * NLEAF + leaf];
    float dy = a_std[(size_t)(2 * l + 1) * NLEAF + leaf];
    *reinterpret_cast<float2*>(out + (size_t)BATCH * OUT_DIM
                               + (size_t)sample * OUT_DIM + 2 * l) =
        make_float2(fminf(fmaxf(dx, -20.f), 2.f),
                    fminf(fmaxf(dy, -20.f), 2.f));
}

extern "C" void kernel_launch(void* const* d_in, const int* in_sizes, int n_in,
                              void* d_out, int out_size, void* d_ws, size_t ws_size,
                              hipStream_t stream) {
    const float* x      = (const float*)d_in[0];
    const float* W_pred = (const float*)d_in[1];
    const float* b_pred = (const float*)d_in[2];
    const float* W_or   = (const float*)d_in[3];
    const float* a_std  = (const float*)d_in[4];
    float* out = (float*)d_out;

    if (ws_size >= (size_t)WB_U32 * 4) {
        uint32_t* Wb = (uint32_t*)d_ws;
        hipLaunchKernelGGL(dgt_prep, dim3((WB_U32 + 255) / 256), dim3(256),
                           0, stream, W_pred, Wb);
        hipLaunchKernelGGL(dgt_b16, dim3(BATCH / 32), dim3(256), 0, stream,
                           x, Wb, W_pred, b_pred, W_or, a_std, out);
    } else {
        hipLaunchKernelGGL(dgt_f32, dim3(BATCH / 32), dim3(256), 0, stream,
                           x, W_pred, b_pred, W_or, a_std, out);
    }
}

// Round 14
// 42.338 us; speedup vs baseline: 1.0952x; 1.0831x over previous
//
#include <hip/hip_runtime.h>
#include <stdint.h>

// DGT forward = binary-tree descent on sign(pred_z[node]) + per-leaf lookup.
// R14 = R13 minus the sched_barrier(0) that serialized the two W-chunk
// loads (R13 post-mortem: per-level latency doubled 2.2k->4.5k cy because
// chunk-B loads could only issue after chunk-A FMAs). Now all 4 uint4 W
// loads issue up front -> one load-wait per level, and R13's register diet
// (x packed bf16 in 16 u32) keeps 3+ waves/EU resident.
//
// Numerics (proven R11-R13, absmax=0.0): both-bf16 dot, EPS_TIE=0.02
// (~12 sigma guard); |z| < EPS -> exact f64 dot on ORIGINAL f32 x and W.
// Spill signature: WRITE_SIZE must stay ~8.2MB (output only).

#define BATCH   65536
#define IN_DIM  256
#define NLEVEL  10
#define NLEAF   1024
#define OUT_DIM 16
#define EPS_TIE 0.02f
#define WB_U32  (1023 * 128)   // packed bf16 W: 128 u32 per row

#define DPP_QUAD_XOR1   0xB1
#define DPP_QUAD_XOR2   0x4E
#define DPP_HALF_MIRROR 0x141

template <int CTRL>
__device__ __forceinline__ float dpp_xfer(float v) {
    return __int_as_float(__builtin_amdgcn_update_dpp(
        0, __float_as_int(v), CTRL, 0xf, 0xf, true));
}
__device__ __forceinline__ float group8_sum(float v) {
    v += dpp_xfer<DPP_QUAD_XOR1>(v);
    v += dpp_xfer<DPP_QUAD_XOR2>(v);
    v += dpp_xfer<DPP_HALF_MIRROR>(v);
    return v;
}
__device__ __forceinline__ float group8_max(float v) {
    v = fmaxf(v, dpp_xfer<DPP_QUAD_XOR1>(v));
    v = fmaxf(v, dpp_xfer<DPP_QUAD_XOR2>(v));
    v = fmaxf(v, dpp_xfer<DPP_HALF_MIRROR>(v));
    return v;
}

__device__ __forceinline__ float blo(uint32_t u) { return __uint_as_float(u << 16); }
__device__ __forceinline__ float bhi(uint32_t u) { return __uint_as_float(u & 0xffff0000u); }

// f32 pair -> packed bf16 (RNE), same rounding as the prep kernel.
__device__ __forceinline__ uint32_t pkbf(float a, float b) {
    uint32_t ua = __float_as_uint(a), ub = __float_as_uint(b);
    uint32_t ra = (ua + 0x7fffu + ((ua >> 16) & 1u)) >> 16;
    uint32_t rb = (ub + 0x7fffu + ((ub >> 16) & 1u)) >> 16;
    return ra | (rb << 16);
}

// ---- prep: W_pred f32 -> packed bf16 (RNE) in d_ws ----
__global__ __launch_bounds__(256) void dgt_prep(
    const float* __restrict__ W, uint32_t* __restrict__ Wb)
{
    int i = blockIdx.x * 256 + threadIdx.x;
    if (i < WB_U32) Wb[i] = pkbf(W[2 * i], W[2 * i + 1]);
}

// Rare exact-sign fallback: f64 dot on ORIGINAL f32 x and W (group-uniform
// entry: z is bitwise-uniform across the 8-lane group).
__device__ __forceinline__ int tree_sign_f64(
    const float* __restrict__ xrow, const float* __restrict__ wrow,
    float bias, int l)
{
    double A0 = 0.0, A1 = 0.0, A2 = 0.0, A3 = 0.0;
    #pragma unroll
    for (int k = 0; k < 4; ++k) {
        float4 xa = *reinterpret_cast<const float4*>(xrow + k * 64 + l * 8);
        float4 xb = *reinterpret_cast<const float4*>(xrow + k * 64 + l * 8 + 4);
        float4 wa = *reinterpret_cast<const float4*>(wrow + k * 64 + l * 8);
        float4 wb = *reinterpret_cast<const float4*>(wrow + k * 64 + l * 8 + 4);
        A0 += (double)xa.x * (double)wa.x; A1 += (double)xa.y * (double)wa.y;
        A2 += (double)xa.z * (double)wa.z; A3 += (double)xa.w * (double)wa.w;
        A0 += (double)xb.x * (double)wb.x; A1 += (double)xb.y * (double)wb.y;
        A2 += (double)xb.z * (double)wb.z; A3 += (double)xb.w * (double)wb.w;
    }
    double Z = (A0 + A1) + (A2 + A3);
    #pragma unroll
    for (int off = 4; off > 0; off >>= 1)   // xor involution: uniform result
        Z += __shfl_xor(Z, off, 64);
    Z += (double)bias;
    return (Z < 0.0) ? 1 : 0;
}

// ---- main: 256 threads = 4 waves; 8-lane groups -> 32 samples/block ----
__global__ __launch_bounds__(256, 3) void dgt_b16(
    const float* __restrict__ x,
    const uint32_t* __restrict__ Wb,
    const float* __restrict__ W_pred,
    const float* __restrict__ b_pred,
    const float* __restrict__ W_or,
    const float* __restrict__ a_std,
    float* __restrict__ out)
{
    const int lane = threadIdx.x & 63;
    const int wid  = threadIdx.x >> 6;
    const int l    = lane & 7;           // lane within 8-group
    const int g    = lane >> 3;          // group (sample) within wave
    const int sample = blockIdx.x * 32 + wid * 8 + g;

    // x: lane l owns elems c + 8l + {0..7} for c in {0,64,128,192};
    // loaded f32, packed to bf16 in 16 u32 registers.
    const float* xrow = x + (size_t)sample * IN_DIM;
    uint32_t p0, p1, p2, p3, p4, p5, p6, p7, p8, p9, p10, p11, p12, p13, p14, p15;
    {
        float4 a0 = *reinterpret_cast<const float4*>(xrow +   0 + l * 8);
        float4 b0 = *reinterpret_cast<const float4*>(xrow +   4 + l * 8);
        float4 a1 = *reinterpret_cast<const float4*>(xrow +  64 + l * 8);
        float4 b1 = *reinterpret_cast<const float4*>(xrow +  68 + l * 8);
        p0 = pkbf(a0.x, a0.y); p1 = pkbf(a0.z, a0.w);
        p2 = pkbf(b0.x, b0.y); p3 = pkbf(b0.z, b0.w);
        p4 = pkbf(a1.x, a1.y); p5 = pkbf(a1.z, a1.w);
        p6 = pkbf(b1.x, b1.y); p7 = pkbf(b1.z, b1.w);
        float4 a2 = *reinterpret_cast<const float4*>(xrow + 128 + l * 8);
        float4 b2 = *reinterpret_cast<const float4*>(xrow + 132 + l * 8);
        float4 a3 = *reinterpret_cast<const float4*>(xrow + 192 + l * 8);
        float4 b3 = *reinterpret_cast<const float4*>(xrow + 196 + l * 8);
        p8  = pkbf(a2.x, a2.y); p9  = pkbf(a2.z, a2.w);
        p10 = pkbf(b2.x, b2.y); p11 = pkbf(b2.z, b2.w);
        p12 = pkbf(a3.x, a3.y); p13 = pkbf(a3.z, a3.w);
        p14 = pkbf(b3.x, b3.y); p15 = pkbf(b3.z, b3.w);
    }

    int node = 0, pos = 0;

    #pragma unroll
    for (int lvl = 0; lvl < NLEVEL; ++lvl) {
        const uint32_t* wb = Wb + (size_t)node * 128;
        float bcur = b_pred[node];   // issues in parallel with W loads

        // ALL FOUR row loads issued up front -> one load-wait per level.
        uint4 A0 = *reinterpret_cast<const uint4*>(wb +  0 + l * 4);
        uint4 A1 = *reinterpret_cast<const uint4*>(wb + 32 + l * 4);
        uint4 B0 = *reinterpret_cast<const uint4*>(wb + 64 + l * 4);
        uint4 B1 = *reinterpret_cast<const uint4*>(wb + 96 + l * 4);

        float a0 = 0.f, a1 = 0.f, a2 = 0.f, a3 = 0.f;
#define FMAU(U, P)                                          \
        a0 += blo(U) * blo(P); a1 += bhi(U) * bhi(P);
#define FMA4(UQ, Pa, Pb, Pc, Pd)                            \
        FMAU(UQ.x, Pa) FMAU(UQ.y, Pb) FMAU(UQ.z, Pc) FMAU(UQ.w, Pd)
        FMA4(A0, p0,  p1,  p2,  p3)
        FMA4(A1, p4,  p5,  p6,  p7)
        FMA4(B0, p8,  p9,  p10, p11)
        FMA4(B1, p12, p13, p14, p15)
#undef FMA4
#undef FMAU

        float z = group8_sum((a0 + a1) + (a2 + a3)) + bcur;

        int right;
        if (__builtin_expect(fabsf(z) >= EPS_TIE, 1))
            right = (z < 0.f) ? 1 : 0;
        else
            right = tree_sign_f64(xrow, W_pred + (size_t)node * IN_DIM,
                                  bcur, l);   // group-uniform entry

        pos  = 2 * pos + right;
        node = 2 * node + 1 + right;
    }
    const int leaf = pos;  // in [0, 1024)

    // Epilogue: lane l covers classes {2l, 2l+1}; tables are cache-resident.
    float zx = W_or[(size_t)(2 * l)     * NLEAF + leaf];
    float zy = W_or[(size_t)(2 * l + 1) * NLEAF + leaf];
    float m  = group8_max(fmaxf(zx, zy));
    float ex = __expf(zx - m), ey = __expf(zy - m);
    float s  = group8_sum(ex + ey);
    *reinterpret_cast<float2*>(out + (size_t)sample * OUT_DIM + 2 * l) =
        make_float2(ex / s, ey / s);

    float dx = a_std[(size_t)(2 * l)     * NLEAF + leaf];
    float dy = a_std[(size_t)(2 * l + 1) * NLEAF + leaf];
    *reinterpret_cast<float2*>(out + (size_t)BATCH * OUT_DIM
                               + (size_t)sample * OUT_DIM + 2 * l) =
        make_float2(fminf(fmaxf(dx, -20.f), 2.f),
                    fminf(fmaxf(dy, -20.f), 2.f));
}

// ---- fallback kernel (ws too small): R8 structure, f32 W direct ----
__device__ __forceinline__ int tree_sign_f64_r8(
    float4 x0, float4 x1, float4 x2, float4 x3,
    float4 x4, float4 x5, float4 x6, float4 x7,
    const float* wrow, float bias, int l)
{
    double A0 = 0.0, A1 = 0.0, A2 = 0.0, A3 = 0.0;
#define ACC64(K, XV)                                                        \
    {                                                                       \
        float4 w = *reinterpret_cast<const float4*>(wrow + (K)*32 + l * 4); \
        A0 += (double)XV.x * (double)w.x; A1 += (double)XV.y * (double)w.y; \
        A2 += (double)XV.z * (double)w.z; A3 += (double)XV.w * (double)w.w; \
    }
    ACC64(0, x0) ACC64(1, x1) ACC64(2, x2) ACC64(3, x3)
    ACC64(4, x4) ACC64(5, x5) ACC64(6, x6) ACC64(7, x7)
#undef ACC64
    double Z = (A0 + A1) + (A2 + A3);
    #pragma unroll
    for (int off = 4; off > 0; off >>= 1)
        Z += __shfl_xor(Z, off, 64);
    Z += (double)bias;
    return (Z < 0.0) ? 1 : 0;
}

__global__ __launch_bounds__(256, 2) void dgt_f32(
    const float* __restrict__ x,
    const float* __restrict__ W_pred,
    const float* __restrict__ b_pred,
    const float* __restrict__ W_or,
    const float* __restrict__ a_std,
    float* __restrict__ out)
{
    const int lane = threadIdx.x & 63;
    const int wid  = threadIdx.x >> 6;
    const int l    = lane & 7;
    const int g    = lane >> 3;
    const int sample = blockIdx.x * 32 + wid * 8 + g;

    const float* xrow = x + (size_t)sample * IN_DIM;
    float4 x0 = *reinterpret_cast<const float4*>(xrow +   0 + l * 4);
    float4 x1 = *reinterpret_cast<const float4*>(xrow +  32 + l * 4);
    float4 x2 = *reinterpret_cast<const float4*>(xrow +  64 + l * 4);
    float4 x3 = *reinterpret_cast<const float4*>(xrow +  96 + l * 4);
    float4 x4 = *reinterpret_cast<const float4*>(xrow + 128 + l * 4);
    float4 x5 = *reinterpret_cast<const float4*>(xrow + 160 + l * 4);
    float4 x6 = *reinterpret_cast<const float4*>(xrow + 192 + l * 4);
    float4 x7 = *reinterpret_cast<const float4*>(xrow + 224 + l * 4);

    int node = 0, pos = 0;
    float bcur = b_pred[0];
    const float* wrow = W_pred;

    #pragma unroll
    for (int lvl = 0; lvl < NLEVEL; ++lvl) {
        float4 w0 = *reinterpret_cast<const float4*>(wrow +   0 + l * 4);
        float4 w1 = *reinterpret_cast<const float4*>(wrow +  32 + l * 4);
        float4 w2 = *reinterpret_cast<const float4*>(wrow +  64 + l * 4);
        float4 w3 = *reinterpret_cast<const float4*>(wrow +  96 + l * 4);
        float4 w4 = *reinterpret_cast<const float4*>(wrow + 128 + l * 4);
        float4 w5 = *reinterpret_cast<const float4*>(wrow + 160 + l * 4);
        float4 w6 = *reinterpret_cast<const float4*>(wrow + 192 + l * 4);
        float4 w7 = *reinterpret_cast<const float4*>(wrow + 224 + l * 4);

        float bL = 0.f, bR = 0.f;
        if (lvl < NLEVEL - 1) {
            bL = b_pred[2 * node + 1];
            bR = b_pred[2 * node + 2];
        }

        float a0, a1, a2, a3;
        a0  = x0.x * w0.x; a1  = x0.y * w0.y; a2  = x0.z * w0.z; a3  = x0.w * w0.w;
        a0 += x1.x * w1.x; a1 += x1.y * w1.y; a2 += x1.z * w1.z; a3 += x1.w * w1.w;
        a0 += x2.x * w2.x; a1 += x2.y * w2.y; a2 += x2.z * w2.z; a3 += x2.w * w2.w;
        a0 += x3.x * w3.x; a1 += x3.y * w3.y; a2 += x3.z * w3.z; a3 += x3.w * w3.w;
        a0 += x4.x * w4.x; a1 += x4.y * w4.y; a2 += x4.z * w4.z; a3 += x4.w * w4.w;
        a0 += x5.x * w5.x; a1 += x5.y * w5.y; a2 += x5.z * w5.z; a3 += x5.w * w5.w;
        a0 += x6.x * w6.x; a1 += x6.y * w6.y; a2 += x6.z * w6.z; a3 += x6.w * w6.w;
        a0 += x7.x * w7.x; a1 += x7.y * w7.y; a2 += x7.z * w7.z; a3 += x7.w * w7.w;
        float z = group8_sum((a0 + a1) + (a2 + a3)) + bcur;

        int right;
        if (__builtin_expect(fabsf(z) >= 1e-3f, 1))
            right = (z < 0.f) ? 1 : 0;
        else
            right = tree_sign_f64_r8(x0, x1, x2, x3, x4, x5, x6, x7,
                                     wrow, bcur, l);

        pos  = 2 * pos + right;
        node = 2 * node + 1 + right;
        if (lvl < NLEVEL - 1) {
            bcur = right ? bR : bL;
            wrow = W_pred + (size_t)node * IN_DIM;
        }
    }
    const int leaf = pos;

    float zx = W_or[(size_t)(2 * l)     * NLEAF + leaf];
    float zy = W_or[(size_t)(2 * l + 1) * NLEAF + leaf];
    float m  = group8_max(fmaxf(zx, zy));
    float ex = __expf(zx - m), ey = __expf(zy - m);
    float s  = group8_sum(ex + ey);
    *reinterpret_cast<float2*>(out + (size_t)sample * OUT_DIM + 2 * l) =
        make_float2(ex / s, ey / s);

    float dx = a_std[(size_t)(2 * l)     * NLEAF + leaf];
    float dy = a_std[(size_t)(2 * l + 1) * NLEAF + leaf];
    *reinterpret_cast<float2*>(out + (size_t)BATCH * OUT_DIM
                               + (size_t)sample * OUT_DIM + 2 * l) =
        make_float2(fminf(fmaxf(dx, -20.f), 2.f),
                    fminf(fmaxf(dy, -20.f), 2.f));
}

extern "C" void kernel_launch(void* const* d_in, const int* in_sizes, int n_in,
                              void* d_out, int out_size, void* d_ws, size_t ws_size,
                              hipStream_t stream) {
    const float* x      = (const float*)d_in[0];
    const float* W_pred = (const float*)d_in[1];
    const float* b_pred = (const float*)d_in[2];
    const float* W_or   = (const float*)d_in[3];
    const float* a_std  = (const float*)d_in[4];
    float* out = (float*)d_out;

    if (ws_size >= (size_t)WB_U32 * 4) {
        uint32_t* Wb = (uint32_t*)d_ws;
        hipLaunchKernelGGL(dgt_prep, dim3((WB_U32 + 255) / 256), dim3(256),
                           0, stream, W_pred, Wb);
        hipLaunchKernelGGL(dgt_b16, dim3(BATCH / 32), dim3(256), 0, stream,
                           x, Wb, W_pred, b_pred, W_or, a_std, out);
    } else {
        hipLaunchKernelGGL(dgt_f32, dim3(BATCH / 32), dim3(256), 0, stream,
                           x, W_pred, b_pred, W_or, a_std, out);
    }
}